// Round 9
// baseline (209.445 us; speedup 1.0000x reference)
//
#include <hip/hip_runtime.h>
#include <math.h>

#define NROWS 131072
#define XC    17      // FLOW_SIZE+1
#define ROWSB 128     // rows per block
#define HID   256
#define NB    128
#define NCOL  1024
#define LOG2E 1.44269504088896340736f

typedef __attribute__((ext_vector_type(8))) short bf16x8;
typedef __attribute__((ext_vector_type(4))) float f32x4;

#if __has_builtin(__builtin_amdgcn_exp2f)
#define EXP2F(v) __builtin_amdgcn_exp2f(v)
#else
#define EXP2F(v) exp2f(v)
#endif
#if __has_builtin(__builtin_amdgcn_rcpf)
#define RCPF(v) __builtin_amdgcn_rcpf(v)
#else
#define RCPF(v) (1.f / (v))
#endif

__device__ __forceinline__ unsigned short f2bf(float f) {
    unsigned int u = __float_as_uint(f);
    return (unsigned short)((u + 0x7FFFu + ((u >> 16) & 1u)) >> 16);  // RNE
}

// 16-lane reduction on the VALU via DPP (validated; no LDS-pipe traffic).
__device__ __forceinline__ float red16(float v) {
    int x;
    x = __builtin_amdgcn_update_dpp(0, __float_as_int(v), 0xB1, 0xF, 0xF, true);
    v += __int_as_float(x);
    x = __builtin_amdgcn_update_dpp(0, __float_as_int(v), 0x4E, 0xF, 0xF, true);
    v += __int_as_float(x);
    x = __builtin_amdgcn_update_dpp(0, __float_as_int(v), 0x141, 0xF, 0xF, true);
    v += __int_as_float(x);
    x = __builtin_amdgcn_update_dpp(0, __float_as_int(v), 0x140, 0xF, 0xF, true);
    v += __int_as_float(x);
    return v;
}

// W2 [256][1024] fp32 -> w2t [col][k-swizzled] bf16 * log2(e). (validated R5/R7)
__global__ void prep_w2(const float* __restrict__ W2, unsigned short* __restrict__ w2t) {
    const int g   = blockIdx.x * 256 + threadIdx.x;   // 32768 threads
    const int col = g >> 5, go = g & 31;              // granule go of col
    const int kg  = (go & ~7) | ((go & 7) ^ (col & 7));  // source k-granule
    unsigned int p[4];
    #pragma unroll
    for (int j = 0; j < 4; ++j) {
        const unsigned short lo = f2bf(W2[(size_t)(kg * 8 + 2 * j) * NCOL + col] * LOG2E);
        const unsigned short hi = f2bf(W2[(size_t)(kg * 8 + 2 * j + 1) * NCOL + col] * LOG2E);
        p[j] = (unsigned int)lo | ((unsigned int)hi << 16);
    }
    *(uint4*)&w2t[(size_t)col * HID + go * 8] = make_uint4(p[0], p[1], p[2], p[3]);
}

__global__ __launch_bounds__(256, 3)
void gplc8(const float* __restrict__ x,
           const float* __restrict__ W1,
           const float* __restrict__ b1,
           const unsigned short* __restrict__ w2t,
           const float* __restrict__ b2,
           float* __restrict__ out)
{
    __shared__ float xs[ROWSB * XC];                       // 8704 B
    __shared__ __align__(16) union {
        unsigned short hb[64 * HID];                       // 32 KB (one 64-row pass)
        struct { unsigned short w2[2][NB * 64]; float b2s[NCOL]; } g;  // 36 KB (t-loop)
    } u;                                                   // total ~45.6 KB -> 3 blocks/CU

    const int tid  = threadIdx.x;
    const int lane = tid & 63;
    const int w    = tid >> 6;        // wave 0..3 -> rows w*32..w*32+31
    const int quad = lane >> 4;
    const int l15  = lane & 15;
    const int grp  = w >> 1;          // which 64-row half this wave's rows sit in
    const int ksw  = (lane & 7) << 3; // B-frag k swizzle (validated: 0 conflicts)
    const size_t r0 = (size_t)blockIdx.x * ROWSB;

    // stage x tile; W1 columns + b1 straight from L2 into regs
    for (int i = tid; i < ROWSB * XC; i += 256) xs[i] = x[r0 * XC + i];
    const int cp = tid & 127, rq = tid >> 7;
    float w1r[16];
    #pragma unroll
    for (int i = 0; i < 8; ++i) {
        const float2 t2 = *(const float2*)&W1[i * HID + 2 * cp];
        w1r[2 * i] = t2.x; w1r[2 * i + 1] = t2.y;
    }
    const float2 b1v = *(const float2*)&b1[2 * cp];
    __syncthreads();

    // ---- phase 1 in TWO 64-row passes through a 32 KB buffer (R9 change:
    // halves hb so total LDS 45.6 KB -> 3 blocks/CU; regs already fit 168).
    bf16x8 afr[2][8];
    #pragma unroll 1
    for (int rb = 0; rb < 2; ++rb) {
        for (int r = 0; r < 32; ++r) {
            const int lr  = rq * 32 + r;          // local row 0..63
            const int row = rb * 64 + lr;
            float a0 = b1v.x, a1 = b1v.y;
            #pragma unroll
            for (int i = 0; i < 8; ++i) {
                const float xv = xs[row * XC + i];
                a0 = fmaf(xv, w1r[2 * i], a0);
                a1 = fmaf(xv, w1r[2 * i + 1], a1);
            }
            a0 = fmaxf(a0, 0.f); a1 = fmaxf(a1, 0.f);
            // granule-XOR swizzle; lr&15 == row&15 (64 is a multiple of 16)
            const int eidx = lr * HID + (((cp >> 2) ^ (lr & 15)) << 3) + ((cp & 3) << 1);
            *(unsigned int*)&u.hb[eidx] = (unsigned int)f2bf(a0) | ((unsigned int)f2bf(a1) << 16);
        }
        __syncthreads();
        if (grp == rb) {   // this wave's 32 rows are in the current pass
            #pragma unroll
            for (int rt = 0; rt < 2; ++rt)
                #pragma unroll
                for (int kf = 0; kf < 8; ++kf) {
                    const int lr = (w & 1) * 32 + rt * 16 + l15;   // lr&15 == l15
                    afr[rt][kf] = *(const bf16x8*)&u.hb[lr * HID + (((kf * 4 + quad) ^ l15) << 3)];
                }
        }
        __syncthreads();   // pass rb consumed; buffer reusable (pass 2 / w2 stage)
    }

    for (int i = tid; i < NCOL; i += 256) u.g.b2s[i] = b2[i] * LOG2E;

    // stage K-chunk n (t=n>>2, kc=n&3): 16 KB linear global_load_lds copy
    auto stage = [&](int n) {
        const int t = n >> 2, kc = n & 3, buf = n & 1;
        #pragma unroll
        for (int j = 0; j < 4; ++j) {
            const int ob = (w * 4 + j) * 512;              // wave-uniform LDS base
            const int c  = (ob >> 6) + (lane >> 3);        // local col 0..127
            const int kl = (lane & 7) << 3;
            const unsigned short* gp = w2t + (size_t)(t * NB + c) * HID + kc * 64 + kl;
            unsigned short* lp = &u.g.w2[buf][ob];
            __builtin_amdgcn_global_load_lds(
                (const __attribute__((address_space(1))) unsigned int*)gp,
                (__attribute__((address_space(3))) unsigned int*)lp, 16, 0, 0);
        }
    };

    float jf[2][4] = {{1.f,1.f,1.f,1.f},{1.f,1.f,1.f,1.f}};
    const int wr = w * 32;

    stage(0);
    #pragma unroll 1
    for (int t = 0; t < 8; ++t) {
        f32x4 acc[2][8];
        #pragma unroll
        for (int rt = 0; rt < 2; ++rt)
            #pragma unroll
            for (int ct = 0; ct < 8; ++ct) acc[rt][ct] = (f32x4){0.f, 0.f, 0.f, 0.f};

        #pragma unroll
        for (int kc = 0; kc < 4; ++kc) {          // STATIC unroll -> static afr idx
            __syncthreads();                       // chunk staged; prev buf readers done
            const int n = t * 4 + kc;
            if (n < 31) stage(n + 1);
            const unsigned short* wsb = u.g.w2[kc & 1];
            #pragma unroll
            for (int ks = 0; ks < 2; ++ks) {
                const int kf = kc * 2 + ks;        // compile-time
                const int klog = ks * 32 + quad * 8;
                #pragma unroll
                for (int ct = 0; ct < 8; ++ct) {
                    const int c = ct * 16 + l15;
                    const bf16x8 bf = *(const bf16x8*)&wsb[c * 64 + (klog ^ ksw)];
                    acc[0][ct] = __builtin_amdgcn_mfma_f32_16x16x32_bf16(afr[0][kf], bf, acc[0][ct], 0, 0, 0);
                    acc[1][ct] = __builtin_amdgcn_mfma_f32_16x16x32_bf16(afr[1][kf], bf, acc[1][ct], 0, 0, 0);
                }
            }
        }

        // ---- fused epilogue for transform t (wave covers full 128-col row)
        float bb[8];
        #pragma unroll
        for (int ct = 0; ct < 8; ++ct) bb[ct] = u.g.b2s[t * NB + ct * 16 + l15];
        #pragma unroll
        for (int rt = 0; rt < 2; ++rt)
            #pragma unroll
            for (int i = 0; i < 4; ++i) {
                const int row = wr + rt * 16 + quad * 4 + i;
                const float alpha = xs[row * XC + 8 + t] * 128.f;   // broadcast
                const float fb = floorf(alpha);
                const int bin = min(max((int)fb, 0), 127);
                const float fr = alpha - fb;
                float e[8];
                #pragma unroll
                for (int ct = 0; ct < 8; ++ct) e[ct] = EXP2F(acc[rt][ct][i] + bb[ct]);
                const float P1 = e[0],      P2 = P1 + e[1], P3 = P2 + e[2], P4 = P3 + e[3];
                const float P5 = P4 + e[4], P6 = P5 + e[5], P7 = P6 + e[6], P8 = P7 + e[7];
                int thr = (bin - l15 + 15) >> 4;           // ceil((bin-l15)/16)
                thr = min(max(thr, 0), 8);
                const float sA = (thr & 1) ? P1 : 0.f;
                const float sB = (thr & 1) ? P3 : P2;
                const float sC = (thr & 1) ? P5 : P4;
                const float sD = (thr & 1) ? P7 : P6;
                const float sE = (thr & 2) ? sB : sA;
                const float sF = (thr & 2) ? sD : sC;
                float num = (thr & 4) ? sF : sE;
                num = (thr >= 8) ? P8 : num;
                const int cb = bin >> 4;
                const float t1 = (cb & 1) ? e[1] : e[0];
                const float t2 = (cb & 1) ? e[3] : e[2];
                const float t3 = (cb & 1) ? e[5] : e[4];
                const float t4 = (cb & 1) ? e[7] : e[6];
                const float u1 = (cb & 2) ? t2 : t1;
                const float u2 = (cb & 2) ? t4 : t3;
                const float es = (cb & 4) ? u2 : u1;
                float eb  = ((bin & 15) == l15) ? es : 0.f;
                float tot = P8;
                tot = red16(tot); num = red16(num); eb = red16(eb);
                const float inv = RCPF(tot);
                jf[rt][i] *= 128.f * eb * inv;
                if (l15 == 0) xs[row * XC + 8 + t] = fmaf(eb, fr, num) * inv;
            }
    }

    // jacobian into xs, then one fully-coalesced block copy-out
    if (l15 == 0) {
        #pragma unroll
        for (int rt = 0; rt < 2; ++rt)
            #pragma unroll
            for (int i = 0; i < 4; ++i) {
                const int row = wr + rt * 16 + quad * 4 + i;
                xs[row * XC + 16] *= jf[rt][i];
            }
    }
    __syncthreads();
    for (int i = tid; i < ROWSB * XC; i += 256) out[r0 * XC + i] = xs[i];
}

extern "C" void kernel_launch(void* const* d_in, const int* in_sizes, int n_in,
                              void* d_out, int out_size, void* d_ws, size_t ws_size,
                              hipStream_t stream) {
    (void)in_sizes; (void)n_in; (void)ws_size; (void)out_size;
    prep_w2<<<(NCOL * HID / 8) / 256, 256, 0, stream>>>(
        (const float*)d_in[3], (unsigned short*)d_ws);
    gplc8<<<NROWS / ROWSB, 256, 0, stream>>>(
        (const float*)d_in[0], (const float*)d_in[1], (const float*)d_in[2],
        (const unsigned short*)d_ws, (const float*)d_in[4], (float*)d_out);
}

// Round 10
// 187.474 us; speedup vs baseline: 1.1172x; 1.1172x over previous
//
#include <hip/hip_runtime.h>
#include <math.h>

#define NROWS 131072
#define XC    17      // FLOW_SIZE+1
#define ROWSB 64      // rows per block
#define HID   256
#define NB    128
#define NCOL  1024
#define LOG2E 1.44269504088896340736f

typedef __attribute__((ext_vector_type(8))) short bf16x8;
typedef __attribute__((ext_vector_type(4))) float f32x4;

#if __has_builtin(__builtin_amdgcn_exp2f)
#define EXP2F(v) __builtin_amdgcn_exp2f(v)
#else
#define EXP2F(v) exp2f(v)
#endif
#if __has_builtin(__builtin_amdgcn_rcpf)
#define RCPF(v) __builtin_amdgcn_rcpf(v)
#else
#define RCPF(v) (1.f / (v))
#endif

__device__ __forceinline__ unsigned short f2bf(float f) {
    unsigned int u = __float_as_uint(f);
    return (unsigned short)((u + 0x7FFFu + ((u >> 16) & 1u)) >> 16);  // RNE
}

// 16-lane reduction on the VALU via DPP (validated; no LDS-pipe traffic).
__device__ __forceinline__ float red16(float v) {
    int x;
    x = __builtin_amdgcn_update_dpp(0, __float_as_int(v), 0xB1, 0xF, 0xF, true);
    v += __int_as_float(x);
    x = __builtin_amdgcn_update_dpp(0, __float_as_int(v), 0x4E, 0xF, 0xF, true);
    v += __int_as_float(x);
    x = __builtin_amdgcn_update_dpp(0, __float_as_int(v), 0x141, 0xF, 0xF, true);
    v += __int_as_float(x);
    x = __builtin_amdgcn_update_dpp(0, __float_as_int(v), 0x140, 0xF, 0xF, true);
    v += __int_as_float(x);
    return v;
}

// W2 [256][1024] fp32 -> w2t [col][k-swizzled] bf16 * log2(e). (validated R5/R7)
__global__ void prep_w2(const float* __restrict__ W2, unsigned short* __restrict__ w2t) {
    const int g   = blockIdx.x * 256 + threadIdx.x;   // 32768 threads
    const int col = g >> 5, go = g & 31;              // granule go of col
    const int kg  = (go & ~7) | ((go & 7) ^ (col & 7));  // source k-granule
    unsigned int p[4];
    #pragma unroll
    for (int j = 0; j < 4; ++j) {
        const unsigned short lo = f2bf(W2[(size_t)(kg * 8 + 2 * j) * NCOL + col] * LOG2E);
        const unsigned short hi = f2bf(W2[(size_t)(kg * 8 + 2 * j + 1) * NCOL + col] * LOG2E);
        p[j] = (unsigned int)lo | ((unsigned int)hi << 16);
    }
    *(uint4*)&w2t[(size_t)col * HID + go * 8] = make_uint4(p[0], p[1], p[2], p[3]);
}

__global__ __launch_bounds__(256, 3)
void gplc9(const float* __restrict__ x,
           const float* __restrict__ W1,
           const float* __restrict__ b1,
           const unsigned short* __restrict__ w2t,
           const float* __restrict__ b2,
           float* __restrict__ out)
{
    __shared__ float xs[ROWSB * XC];                       // 4352 B
    __shared__ float red[ROWSB][2][3];                     // 1536 B
    __shared__ __align__(16) union {
        unsigned short hb[ROWSB * HID];                    // 32 KB (phase 1, SINGLE pass)
        struct { unsigned short w2[2][NB * 64]; float b2s[NCOL]; } g;  // 36 KB (t-loop)
    } u;                                                   // total 42752 B -> 3 blocks/CU

    const int tid  = threadIdx.x;
    const int lane = tid & 63;
    const int w    = tid >> 6;        // 4 waves: (grp, half)
    const int quad = lane >> 4;
    const int l15  = lane & 15;
    const int grp  = w >> 1;          // rows grp*32 .. +31
    const int half = w & 1;           // col half (64 cols)
    const int ksw  = (lane & 7) << 3; // B-frag k swizzle (validated: 0 conflicts)
    const size_t r0 = (size_t)blockIdx.x * ROWSB;

    // stage x tile; W1 columns + b1 straight from L2 into regs
    for (int i = tid; i < ROWSB * XC; i += 256) xs[i] = x[r0 * XC + i];
    const int cp = tid & 127, rq = tid >> 7;
    float w1r[16];
    #pragma unroll
    for (int i = 0; i < 8; ++i) {
        const float2 t2 = *(const float2*)&W1[i * HID + 2 * cp];
        w1r[2 * i] = t2.x; w1r[2 * i + 1] = t2.y;
    }
    const float2 b1v = *(const float2*)&b1[2 * cp];
    __syncthreads();

    // ---- phase 1: h = relu(xA@W1+b1) -> bf16 LDS (64 rows, one pass,
    // UNCONDITIONAL -> afr stays in registers; R9's conditional init spilled)
    for (int r = 0; r < 32; ++r) {
        const int row = rq * 32 + r;
        float a0 = b1v.x, a1 = b1v.y;
        #pragma unroll
        for (int i = 0; i < 8; ++i) {
            const float xv = xs[row * XC + i];
            a0 = fmaf(xv, w1r[2 * i], a0);
            a1 = fmaf(xv, w1r[2 * i + 1], a1);
        }
        a0 = fmaxf(a0, 0.f); a1 = fmaxf(a1, 0.f);
        const int eidx = row * HID + (((cp >> 2) ^ (row & 15)) << 3) + ((cp & 3) << 1);
        *(unsigned int*)&u.hb[eidx] = (unsigned int)f2bf(a0) | ((unsigned int)f2bf(a1) << 16);
    }
    __syncthreads();

    // ---- A-fragment register cache: 32 rows x 256 K per wave (64 VGPR),
    // straight-line static-index loads only.
    bf16x8 afr[2][8];
    #pragma unroll
    for (int rt = 0; rt < 2; ++rt)
        #pragma unroll
        for (int kf = 0; kf < 8; ++kf) {
            const int row = grp * 32 + rt * 16 + l15;    // row&15 == l15
            afr[rt][kf] = *(const bf16x8*)&u.hb[row * HID + (((kf * 4 + quad) ^ l15) << 3)];
        }
    __syncthreads();   // hb dead; union region becomes w2 dbuf + b2s

    for (int i = tid; i < NCOL; i += 256) u.g.b2s[i] = b2[i] * LOG2E;

    // stage K-chunk n (t=n>>2, kc=n&3): 16 KB linear global_load_lds copy
    auto stage = [&](int n) {
        const int t = n >> 2, kc = n & 3, buf = n & 1;
        #pragma unroll
        for (int j = 0; j < 4; ++j) {
            const int ob = (w * 4 + j) * 512;              // wave-uniform LDS base
            const int c  = (ob >> 6) + (lane >> 3);        // local col 0..127
            const int kl = (lane & 7) << 3;
            const unsigned short* gp = w2t + (size_t)(t * NB + c) * HID + kc * 64 + kl;
            unsigned short* lp = &u.g.w2[buf][ob];
            __builtin_amdgcn_global_load_lds(
                (const __attribute__((address_space(1))) unsigned int*)gp,
                (__attribute__((address_space(3))) unsigned int*)lp, 16, 0, 0);
        }
    };

    float jfr = 1.f;   // jacobian product, threads 0..63 (row = tid)

    stage(0);
    #pragma unroll 1
    for (int t = 0; t < 8; ++t) {
        f32x4 acc[2][4];
        #pragma unroll
        for (int rt = 0; rt < 2; ++rt)
            #pragma unroll
            for (int ct = 0; ct < 4; ++ct) acc[rt][ct] = (f32x4){0.f, 0.f, 0.f, 0.f};

        #pragma unroll
        for (int kc = 0; kc < 4; ++kc) {          // STATIC unroll -> static afr idx
            __syncthreads();                       // chunk staged; prev buf readers done
            const int n = t * 4 + kc;
            if (n < 31) stage(n + 1);
            if (kc == 0 && t > 0 && tid < ROWSB) {   // deferred finish of t-1 (R4/R8-validated)
                const int tf = t - 1;
                const float tot = red[tid][0][0] + red[tid][1][0];
                const float num = red[tid][0][1] + red[tid][1][1];
                const float eb  = red[tid][0][2] + red[tid][1][2];
                const float alpha = xs[tid * XC + 8 + tf] * 128.f;
                const float fr  = alpha - floorf(alpha);
                const float inv = RCPF(tot);
                xs[tid * XC + 8 + tf] = fmaf(eb, fr, num) * inv;
                jfr *= 128.f * eb * inv;
            }
            const unsigned short* wsb = u.g.w2[kc & 1];
            #pragma unroll
            for (int ks = 0; ks < 2; ++ks) {
                const int kf = kc * 2 + ks;        // compile-time
                const int klog = ks * 32 + quad * 8;
                #pragma unroll
                for (int ct = 0; ct < 4; ++ct) {
                    const int c = half * 64 + ct * 16 + l15;
                    const bf16x8 bf = *(const bf16x8*)&wsb[c * 64 + (klog ^ ksw)];
                    acc[0][ct] = __builtin_amdgcn_mfma_f32_16x16x32_bf16(afr[0][kf], bf, acc[0][ct], 0, 0, 0);
                    acc[1][ct] = __builtin_amdgcn_mfma_f32_16x16x32_bf16(afr[1][kf], bf, acc[1][ct], 0, 0, 0);
                }
            }
        }

        // ---- partial epilogue (this col-half) -> red[]  (R8-validated)
        float bb[4];
        #pragma unroll
        for (int ct = 0; ct < 4; ++ct)
            bb[ct] = u.g.b2s[t * NB + half * 64 + ct * 16 + l15];
        #pragma unroll
        for (int rt = 0; rt < 2; ++rt)
            #pragma unroll
            for (int i = 0; i < 4; ++i) {
                const int row = grp * 32 + rt * 16 + quad * 4 + i;
                const float alpha = xs[row * XC + 8 + t] * 128.f;   // broadcast
                const float fb = floorf(alpha);
                const int bin = min(max((int)fb, 0), 127);
                float e0 = EXP2F(acc[rt][0][i] + bb[0]);
                float e1 = EXP2F(acc[rt][1][i] + bb[1]);
                float e2 = EXP2F(acc[rt][2][i] + bb[2]);
                float e3 = EXP2F(acc[rt][3][i] + bb[3]);
                const float P1 = e0, P2 = P1 + e1, P3 = P2 + e2, P4 = P3 + e3;
                int thr = (bin - half * 64 - l15 + 15) >> 4;
                thr = min(max(thr, 0), 4);
                const float sa = (thr & 1) ? P1 : 0.f;
                const float sb = (thr & 1) ? P3 : P2;
                const float sn = (thr & 2) ? sb : sa;
                float num = (thr >= 4) ? P4 : sn;
                const int cb = (bin >> 4) & 3;
                const float ea = (cb & 1) ? e1 : e0;
                const float ec = (cb & 1) ? e3 : e2;
                const float es = (cb & 2) ? ec : ea;
                float eb  = (((bin >> 6) == half) && ((bin & 15) == l15)) ? es : 0.f;
                float tot = P4;
                tot = red16(tot); num = red16(num); eb = red16(eb);
                if (l15 == 0) {
                    red[row][half][0] = tot;
                    red[row][half][1] = num;
                    red[row][half][2] = eb;
                }
            }
    }

    __syncthreads();
    if (tid < ROWSB) {     // finish t=7 + jacobian
        const float tot = red[tid][0][0] + red[tid][1][0];
        const float num = red[tid][0][1] + red[tid][1][1];
        const float eb  = red[tid][0][2] + red[tid][1][2];
        const float alpha = xs[tid * XC + 15] * 128.f;
        const float fr  = alpha - floorf(alpha);
        const float inv = RCPF(tot);
        xs[tid * XC + 15] = fmaf(eb, fr, num) * inv;
        jfr *= 128.f * eb * inv;
        xs[tid * XC + 16] *= jfr;
    }
    __syncthreads();
    for (int i = tid; i < ROWSB * XC; i += 256) out[r0 * XC + i] = xs[i];
}

extern "C" void kernel_launch(void* const* d_in, const int* in_sizes, int n_in,
                              void* d_out, int out_size, void* d_ws, size_t ws_size,
                              hipStream_t stream) {
    (void)in_sizes; (void)n_in; (void)ws_size; (void)out_size;
    prep_w2<<<(NCOL * HID / 8) / 256, 256, 0, stream>>>(
        (const float*)d_in[3], (unsigned short*)d_ws);
    gplc9<<<NROWS / ROWSB, 256, 0, stream>>>(
        (const float*)d_in[0], (const float*)d_in[1], (const float*)d_in[2],
        (const unsigned short*)d_ws, (const float*)d_in[4], (float*)d_out);
}

// Round 11
// 174.722 us; speedup vs baseline: 1.1987x; 1.0730x over previous
//
#include <hip/hip_runtime.h>
#include <math.h>

#define NROWS 131072
#define XC    17      // FLOW_SIZE+1
#define ROWSB 128     // rows per block
#define HID   256
#define NB    128
#define NCOL  1024
#define LOG2E 1.44269504088896340736f

typedef __attribute__((ext_vector_type(8))) short bf16x8;
typedef __attribute__((ext_vector_type(4))) float f32x4;

#if __has_builtin(__builtin_amdgcn_exp2f)
#define EXP2F(v) __builtin_amdgcn_exp2f(v)
#else
#define EXP2F(v) exp2f(v)
#endif
#if __has_builtin(__builtin_amdgcn_rcpf)
#define RCPF(v) __builtin_amdgcn_rcpf(v)
#else
#define RCPF(v) (1.f / (v))
#endif

__device__ __forceinline__ unsigned short f2bf(float f) {
    unsigned int u = __float_as_uint(f);
    return (unsigned short)((u + 0x7FFFu + ((u >> 16) & 1u)) >> 16);  // RNE
}

// 16-lane reduction on the VALU via DPP (validated; no LDS-pipe traffic).
__device__ __forceinline__ float red16(float v) {
    int x;
    x = __builtin_amdgcn_update_dpp(0, __float_as_int(v), 0xB1, 0xF, 0xF, true);
    v += __int_as_float(x);
    x = __builtin_amdgcn_update_dpp(0, __float_as_int(v), 0x4E, 0xF, 0xF, true);
    v += __int_as_float(x);
    x = __builtin_amdgcn_update_dpp(0, __float_as_int(v), 0x141, 0xF, 0xF, true);
    v += __int_as_float(x);
    x = __builtin_amdgcn_update_dpp(0, __float_as_int(v), 0x140, 0xF, 0xF, true);
    v += __int_as_float(x);
    return v;
}

// W2 [256][1024] fp32 -> w2t [col][k-swizzled] bf16 * log2(e). (validated R5/R7)
__global__ void prep_w2(const float* __restrict__ W2, unsigned short* __restrict__ w2t) {
    const int g   = blockIdx.x * 256 + threadIdx.x;   // 32768 threads
    const int col = g >> 5, go = g & 31;              // granule go of col
    const int kg  = (go & ~7) | ((go & 7) ^ (col & 7));  // source k-granule
    unsigned int p[4];
    #pragma unroll
    for (int j = 0; j < 4; ++j) {
        const unsigned short lo = f2bf(W2[(size_t)(kg * 8 + 2 * j) * NCOL + col] * LOG2E);
        const unsigned short hi = f2bf(W2[(size_t)(kg * 8 + 2 * j + 1) * NCOL + col] * LOG2E);
        p[j] = (unsigned int)lo | ((unsigned int)hi << 16);
    }
    *(uint4*)&w2t[(size_t)col * HID + go * 8] = make_uint4(p[0], p[1], p[2], p[3]);
}

__global__ __launch_bounds__(256, 2)
void gplc10(const float* __restrict__ x,
            const float* __restrict__ W1,
            const float* __restrict__ b1,
            const unsigned short* __restrict__ w2t,
            const float* __restrict__ b2,
            float* __restrict__ out)
{
    __shared__ float xs[ROWSB * XC];                       // 8704 B
    __shared__ __align__(16) union {
        unsigned short hb[ROWSB * HID];                    // 64 KB (phase 1 + A-frag load)
        struct { unsigned short w2[2][NB * 128]; float b2s[NCOL]; } g;  // 64+4 KB (t-loop)
    } u;                                                   // total ~76.5 KB -> 2 blocks/CU

    const int tid  = threadIdx.x;
    const int lane = tid & 63;
    const int w    = tid >> 6;        // wave 0..3 -> rows w*32..w*32+31
    const int quad = lane >> 4;
    const int l15  = lane & 15;
    const int wr   = w * 32;
    const int ksw  = (lane & 7) << 3; // B-frag k swizzle (validated: 0 conflicts)
    const size_t r0 = (size_t)blockIdx.x * ROWSB;

    // stage x tile; W1 columns + b1 straight from L2 into regs
    for (int i = tid; i < ROWSB * XC; i += 256) xs[i] = x[r0 * XC + i];
    const int cp = tid & 127, hlf = tid >> 7;
    float w1r[16];
    #pragma unroll
    for (int i = 0; i < 8; ++i) {
        const float2 t2 = *(const float2*)&W1[i * HID + 2 * cp];
        w1r[2 * i] = t2.x; w1r[2 * i + 1] = t2.y;
    }
    const float2 b1v = *(const float2*)&b1[2 * cp];
    __syncthreads();

    // ---- phase 1: h = relu(xA@W1+b1) -> bf16 LDS, granule-XOR row swizzle
    for (int r = 0; r < 64; ++r) {
        const int row = hlf * 64 + r;
        float a0 = b1v.x, a1 = b1v.y;
        #pragma unroll
        for (int i = 0; i < 8; ++i) {
            const float xv = xs[row * XC + i];
            a0 = fmaf(xv, w1r[2 * i], a0);
            a1 = fmaf(xv, w1r[2 * i + 1], a1);
        }
        a0 = fmaxf(a0, 0.f); a1 = fmaxf(a1, 0.f);
        const int eidx = row * HID + (((cp >> 2) ^ (row & 15)) << 3) + ((cp & 3) << 1);
        *(unsigned int*)&u.hb[eidx] = (unsigned int)f2bf(a0) | ((unsigned int)f2bf(a1) << 16);
    }
    __syncthreads();

    // ---- A-fragment register cache: 32 rows x 256 K per wave (64 VGPR).
    // ALL indices compile-time (dynamic idx / conditional init -> scratch spill).
    bf16x8 afr[2][8];
    #pragma unroll
    for (int rt = 0; rt < 2; ++rt)
        #pragma unroll
        for (int kf = 0; kf < 8; ++kf) {
            const int row = wr + rt * 16 + l15;    // row&15 == l15
            afr[rt][kf] = *(const bf16x8*)&u.hb[row * HID + (((kf * 4 + quad) ^ l15) << 3)];
        }
    __syncthreads();   // hb dead; union region becomes w2 dbuf + b2s

    for (int i = tid; i < NCOL; i += 256) u.g.b2s[i] = b2[i] * LOG2E;

    // stage half-t chunk n (t=n>>1, kc=n&1): 32 KB linear global_load_lds copy.
    // R11 change: KC=128 -> 16 barriers/block (was 32), 2x prefetch window.
    auto stage = [&](int n) {
        const int t = n >> 1, kc = n & 1, buf = n & 1;
        #pragma unroll
        for (int j = 0; j < 8; ++j) {
            const int ob = (w * 8 + j) * 512;              // wave-uniform LDS elem base
            const int c  = (ob >> 7) + (lane >> 4);        // local col 0..127
            const int kl = (lane & 15) << 3;               // k-local 0..127 (swizzled layout)
            const unsigned short* gp = w2t + (size_t)(t * NB + c) * HID + kc * 128 + kl;
            unsigned short* lp = &u.g.w2[buf][ob];
            __builtin_amdgcn_global_load_lds(
                (const __attribute__((address_space(1))) unsigned int*)gp,
                (__attribute__((address_space(3))) unsigned int*)lp, 16, 0, 0);
        }
    };

    float jf[2][4] = {{1.f,1.f,1.f,1.f},{1.f,1.f,1.f,1.f}};

    stage(0);
    #pragma unroll 1
    for (int t = 0; t < 8; ++t) {
        f32x4 acc[2][8];
        #pragma unroll
        for (int rt = 0; rt < 2; ++rt)
            #pragma unroll
            for (int ct = 0; ct < 8; ++ct) acc[rt][ct] = (f32x4){0.f, 0.f, 0.f, 0.f};

        #pragma unroll
        for (int kc = 0; kc < 2; ++kc) {          // STATIC unroll -> static afr idx
            __syncthreads();                       // chunk n staged; prev buf readers done
            const int n = t * 2 + kc;
            if (n < 15) stage(n + 1);
            const unsigned short* wsb = u.g.w2[n & 1];
            #pragma unroll
            for (int ks = 0; ks < 4; ++ks) {
                const int kf = kc * 4 + ks;        // compile-time
                const int klog = ks * 32 + quad * 8;   // k within 128-chunk
                #pragma unroll
                for (int ct = 0; ct < 8; ++ct) {
                    const int c = ct * 16 + l15;
                    const bf16x8 bf = *(const bf16x8*)&wsb[c * 128 + (klog ^ ksw)];
                    acc[0][ct] = __builtin_amdgcn_mfma_f32_16x16x32_bf16(afr[0][kf], bf, acc[0][ct], 0, 0, 0);
                    acc[1][ct] = __builtin_amdgcn_mfma_f32_16x16x32_bf16(afr[1][kf], bf, acc[1][ct], 0, 0, 0);
                }
            }
        }

        // ---- fused epilogue for transform t (wave covers full 128-col row)
        float bb[8];
        #pragma unroll
        for (int ct = 0; ct < 8; ++ct) bb[ct] = u.g.b2s[t * NB + ct * 16 + l15];
        #pragma unroll
        for (int rt = 0; rt < 2; ++rt)
            #pragma unroll
            for (int i = 0; i < 4; ++i) {
                const int row = wr + rt * 16 + quad * 4 + i;
                const float alpha = xs[row * XC + 8 + t] * 128.f;   // broadcast
                const float fb = floorf(alpha);
                const int bin = min(max((int)fb, 0), 127);
                const float fr = alpha - fb;
                float e[8];
                #pragma unroll
                for (int ct = 0; ct < 8; ++ct) e[ct] = EXP2F(acc[rt][ct][i] + bb[ct]);
                const float P1 = e[0],      P2 = P1 + e[1], P3 = P2 + e[2], P4 = P3 + e[3];
                const float P5 = P4 + e[4], P6 = P5 + e[5], P7 = P6 + e[6], P8 = P7 + e[7];
                int thr = (bin - l15 + 15) >> 4;           // ceil((bin-l15)/16)
                thr = min(max(thr, 0), 8);
                const float sA = (thr & 1) ? P1 : 0.f;
                const float sB = (thr & 1) ? P3 : P2;
                const float sC = (thr & 1) ? P5 : P4;
                const float sD = (thr & 1) ? P7 : P6;
                const float sE = (thr & 2) ? sB : sA;
                const float sF = (thr & 2) ? sD : sC;
                float num = (thr & 4) ? sF : sE;
                num = (thr >= 8) ? P8 : num;
                const int cb = bin >> 4;
                const float t1 = (cb & 1) ? e[1] : e[0];
                const float t2 = (cb & 1) ? e[3] : e[2];
                const float t3 = (cb & 1) ? e[5] : e[4];
                const float t4 = (cb & 1) ? e[7] : e[6];
                const float u1 = (cb & 2) ? t2 : t1;
                const float u2 = (cb & 2) ? t4 : t3;
                const float es = (cb & 4) ? u2 : u1;
                float eb  = ((bin & 15) == l15) ? es : 0.f;
                float tot = P8;
                tot = red16(tot); num = red16(num); eb = red16(eb);
                const float inv = RCPF(tot);
                jf[rt][i] *= 128.f * eb * inv;
                if (l15 == 0) xs[row * XC + 8 + t] = fmaf(eb, fr, num) * inv;
            }
    }

    // jacobian into xs, then one fully-coalesced block copy-out
    if (l15 == 0) {
        #pragma unroll
        for (int rt = 0; rt < 2; ++rt)
            #pragma unroll
            for (int i = 0; i < 4; ++i) {
                const int row = wr + rt * 16 + quad * 4 + i;
                xs[row * XC + 16] *= jf[rt][i];
            }
    }
    __syncthreads();
    for (int i = tid; i < ROWSB * XC; i += 256) out[r0 * XC + i] = xs[i];
}

extern "C" void kernel_launch(void* const* d_in, const int* in_sizes, int n_in,
                              void* d_out, int out_size, void* d_ws, size_t ws_size,
                              hipStream_t stream) {
    (void)in_sizes; (void)n_in; (void)ws_size; (void)out_size;
    prep_w2<<<(NCOL * HID / 8) / 256, 256, 0, stream>>>(
        (const float*)d_in[3], (unsigned short*)d_ws);
    gplc10<<<NROWS / ROWSB, 256, 0, stream>>>(
        (const float*)d_in[0], (const float*)d_in[1], (const float*)d_in[2],
        (const unsigned short*)d_ws, (const float*)d_in[4], (float*)d_out);
}